// Round 5
// baseline (211.806 us; speedup 1.0000x reference)
//
#include <hip/hip_runtime.h>
#include <hip/hip_bf16.h>
#include <cstdint>
#include <cstddef>

typedef __attribute__((ext_vector_type(8))) short s8v;    // 8 x bf16 bits (4 VGPRs)
typedef __attribute__((ext_vector_type(4))) float f4v;    // 16x16 MFMA accumulator
typedef __attribute__((ext_vector_type(16))) float f16v;  // 32x32 MFMA accumulator
typedef __attribute__((ext_vector_type(4))) unsigned u4v;

#define MFMA_BF16(a, b, c) __builtin_amdgcn_mfma_f32_16x16x32_bf16((a), (b), (c), 0, 0, 0)
#define MFMA32(a, b, c) __builtin_amdgcn_mfma_f32_32x32x16_bf16((a), (b), (c), 0, 0, 0)

// round-to-nearest-even f32 -> bf16 bits (finite inputs)
__device__ __forceinline__ short f2bf(float f) {
    unsigned u = __builtin_bit_cast(unsigned, f);
    u += 0x7FFFu + ((u >> 16) & 1u);
    return (short)(u >> 16);
}

// packed f32 pair -> 2 x bf16 in one dword (lo = a, hi = b)
__device__ __forceinline__ unsigned cvt_pk_bf16(float a, float b) {
    unsigned r;
    asm("v_cvt_pk_bf16_f32 %0, %1, %2" : "=v"(r) : "v"(a), "v"(b));
    return r;
}

// async global->LDS, 16B per lane. lds dest must be wave-uniform base (+lane*16 by HW).
#define GLDS16(gsrc, ldst)                                                                   \
    __builtin_amdgcn_global_load_lds(                                                        \
        (const __attribute__((address_space(1))) unsigned int*)(gsrc),                       \
        (__attribute__((address_space(3))) unsigned int*)(ldst), 16, 0, 0)

// ---------------------------------------------------------------------------
// x fp32 -> bf16 (vectorized)
// ---------------------------------------------------------------------------
__global__ void convert_x(const float4* __restrict__ in, short4* __restrict__ out, int n4) {
    int i = blockIdx.x * blockDim.x + threadIdx.x;
    int stride = gridDim.x * blockDim.x;
    for (; i < n4; i += stride) {
        float4 v = in[i];
        short4 o;
        o.x = f2bf(v.x); o.y = f2bf(v.y); o.z = f2bf(v.z); o.w = f2bf(v.w);
        out[i] = o;
    }
}

// ---------------------------------------------------------------------------
// W[k][n] fp32 -> Wt[n][k] bf16   (1024x1024 each, z selects which weight)
// ---------------------------------------------------------------------------
__global__ void transpose_w(const float* __restrict__ a0, const float* __restrict__ a1,
                            const float* __restrict__ a2, const float* __restrict__ a3,
                            short* __restrict__ outb) {
    const float* src = (blockIdx.z == 0) ? a0 : (blockIdx.z == 1) ? a1 : (blockIdx.z == 2) ? a2 : a3;
    short* dst = outb + (size_t)blockIdx.z * 1048576;
    __shared__ float t[32][33];
    const int n0 = blockIdx.x * 32, k0 = blockIdx.y * 32;
    const int tid = threadIdx.x;
    const int rr = tid >> 3, c4 = (tid & 7) * 4;
    float4 v = *(const float4*)(src + (size_t)(k0 + rr) * 1024 + n0 + c4);
    t[rr][c4 + 0] = v.x; t[rr][c4 + 1] = v.y; t[rr][c4 + 2] = v.z; t[rr][c4 + 3] = v.w;
    __syncthreads();
    short4 o;
    o.x = f2bf(t[c4 + 0][rr]); o.y = f2bf(t[c4 + 1][rr]);
    o.z = f2bf(t[c4 + 2][rr]); o.w = f2bf(t[c4 + 3][rr]);
    *(short4*)(dst + (size_t)(n0 + rr) * 1024 + k0 + c4) = o;
}

// ---------------------------------------------------------------------------
// GEMM: C = op(A[M][K] @ B[N][K]^T + bias) * alpha    (A,B bf16 row-major, K%64==0)
// MODE 0: C[m][n] = (dot + bias[n]) * alpha          (OUT_T float or bf16)
// MODE 1: transposed store for V (row=n-dim, col=x-row), bf16.
// 128x128 tile, BK=64, 4 waves, 4x4 16x16x32 MFMA per wave. (0-conflict pattern)
// ---------------------------------------------------------------------------
template <typename OUT_T, int MODE>
__global__ __launch_bounds__(256, 2) void gemm_bt(const short* __restrict__ A,
                                                  const short* __restrict__ B,
                                                  const float* __restrict__ bias,
                                                  OUT_T* __restrict__ C,
                                                  int M, int N, int K, float alpha) {
    __shared__ short As[128 * 64];
    __shared__ short Bs[128 * 64];
    const int tid = threadIdx.x;
    const int lane = tid & 63;
    const int w = tid >> 6;
    const int wr = w >> 1, wc = w & 1;
    const int m0 = blockIdx.y * 128, n0 = blockIdx.x * 128;
    const int KB = K * 2;  // row bytes

    f4v acc[4][4] = {};

    for (int kt = 0; kt < K; kt += 64) {
#pragma unroll
        for (int i = 0; i < 4; i++) {
            int o = tid * 16 + i * 4096;      // linear LDS byte offset
            int r = o >> 7;                   // tile row
            int cs = (o & 127) ^ ((r & 7) << 4);  // pre-swizzled source column byte
            GLDS16((const char*)A + (size_t)(m0 + r) * KB + kt * 2 + cs,
                   (char*)As + (w * 1024 + i * 4096));
            GLDS16((const char*)B + (size_t)(n0 + r) * KB + kt * 2 + cs,
                   (char*)Bs + (w * 1024 + i * 4096));
        }
        __syncthreads();
#pragma unroll
        for (int kk = 0; kk < 2; kk++) {
            s8v af[4], bf[4];
#pragma unroll
            for (int mi = 0; mi < 4; mi++) {
                int r = wr * 64 + mi * 16 + (lane & 15);
                int cb = (((lane >> 4) * 16) + kk * 64) ^ ((r & 7) << 4);
                af[mi] = *(const s8v*)((const char*)As + r * 128 + cb);
            }
#pragma unroll
            for (int ni = 0; ni < 4; ni++) {
                int r = wc * 64 + ni * 16 + (lane & 15);
                int cb = (((lane >> 4) * 16) + kk * 64) ^ ((r & 7) << 4);
                bf[ni] = *(const s8v*)((const char*)Bs + r * 128 + cb);
            }
#pragma unroll
            for (int mi = 0; mi < 4; mi++)
#pragma unroll
                for (int ni = 0; ni < 4; ni++)
                    acc[mi][ni] = MFMA_BF16(af[mi], bf[ni], acc[mi][ni]);
        }
        __syncthreads();
    }

    // epilogue: C/D layout col=lane&15, row=(lane>>4)*4+j
#pragma unroll
    for (int mi = 0; mi < 4; mi++) {
#pragma unroll
        for (int ni = 0; ni < 4; ni++) {
            int row = m0 + wr * 64 + mi * 16 + ((lane >> 4) << 2);
            int col = n0 + wc * 64 + ni * 16 + (lane & 15);
#pragma unroll
            for (int j = 0; j < 4; j++) {
                float v = acc[mi][ni][j];
                if constexpr (MODE == 0) {
                    v = (v + bias[col]) * alpha;
                    size_t idx = (size_t)(row + j) * N + col;
                    if constexpr (sizeof(OUT_T) == 2) C[idx] = (OUT_T)f2bf(v);
                    else C[idx] = v;
                } else {
                    v = (v + bias[row + j]) * alpha;
                    size_t idx = (size_t)(col >> 11) * (2048 * 1024) + (size_t)(row + j) * 2048 + (col & 2047);
                    C[idx] = (OUT_T)f2bf(v);
                }
            }
        }
    }
}

// ---------------------------------------------------------------------------
// Flash attention fwd v4: 32x32x16 MFMA, 64 q-rows per wave (2 q-groups),
// in-register P via cvt_pk + permlane32_swap, lane-local softmax, defer-max,
// double-buffered K/V, conflict-free bit4<->6-swapped LDS swizzle.
// Q pre-scaled by 0.125*log2e in its GEMM epilogue, so P = exp2(S - m).
// Qb,Kb: [B*S][1024] bf16 (head at cols h*64..)   Vtb: [(b*1024+h*64+d)][2048] bf16
// AOb:   [B*S][1024] bf16
// 4 waves/block, 64 q/wave (256/block), KVBLK=64, 32 k-tiles, grid (8, 64).
// LDS storage: logical (r,c) at physical  P(c) ^ ((r&7)<<4),  P = swap bits 4,6.
// Fragment read col: H*64 + (idx&1)*32 + (idx>>1)*16  -> any quad-pair's H=0/H=1
// slot-sets differ in bit 6 (disjoint); any 8 consecutive lanes span all 8 slots.
// ---------------------------------------------------------------------------
__global__ __launch_bounds__(256, 2) void attn_fwd(const short* __restrict__ Qb,
                                                   const short* __restrict__ Kb,
                                                   const short* __restrict__ Vtb,
                                                   short* __restrict__ AOb) {
    __shared__ short Ks[2][64 * 64];   // [s][d] swizzled, double buffered
    __shared__ short Vs[2][64 * 64];   // [d][s] swizzled, double buffered

    const int tid = threadIdx.x, lane = tid & 63, w = tid >> 6;
    const int l5 = lane & 31, H = lane >> 5;
    const int qt = blockIdx.x;        // 0..7
    const int bh = blockIdx.y;        // 0..63
    const int b = bh >> 4, h = bh & 15;
    const int q0 = qt * 256 + w * 64; // within-batch q row base for this wave

    // Q fragments (B-operand: col q=l5 within group g, d = st*16 + H*8 + 0..7)
    s8v qf[2][4];
#pragma unroll
    for (int g = 0; g < 2; g++)
#pragma unroll
        for (int st = 0; st < 4; st++)
            qf[g][st] = *(const s8v*)(Qb + (size_t)(b * 2048 + q0 + g * 32 + l5) * 1024 +
                                      h * 64 + st * 16 + H * 8);

    f16v oacc[2][2] = {};              // [g][dt]: O^T col q=l5, row d = dt*32+8*(r>>2)+4H+(r&3)
    float m_[2] = {-1e30f, -1e30f};
    float l_[2] = {0.f, 0.f};

    auto STAGE = [&](int s0, int bi) {
#pragma unroll
        for (int i = 0; i < 2; i++) {
            int o = tid * 16 + i * 4096;
            int r = o >> 7;
            int px = (o & 127) ^ ((r & 7) << 4);
            int cs = (px & 0x2F) | ((px & 16) << 2) | ((px & 64) >> 2);  // P(px): swap bits 4<->6
            GLDS16((const char*)Kb + (size_t)(b * 2048 + s0 + r) * 2048 + h * 128 + cs,
                   (char*)Ks[bi] + w * 1024 + i * 4096);
            GLDS16((const char*)Vtb + (size_t)(b * 1024 + h * 64 + r) * 4096 + (size_t)s0 * 2 + cs,
                   (char*)Vs[bi] + w * 1024 + i * 4096);
        }
    };

    STAGE(0, 0);
    __syncthreads();

    int cur = 0;
    for (int t = 0; t < 32; t++) {
        if (t < 31) STAGE((t + 1) * 64, cur ^ 1);

        // S^T = K Q^T : two 32x32 k-tiles, 4 K-steps of 16 over d, 2 q-groups
        f16v sf[2][2] = {};            // [g][kt]
        __builtin_amdgcn_s_setprio(1);
#pragma unroll
        for (int kt = 0; kt < 2; kt++) {
            int r = kt * 32 + l5;
            int swz = (r & 7) << 4;
#pragma unroll
            for (int st = 0; st < 4; st++) {
                int col = (H << 6) | ((st & 1) << 5) | ((st >> 1) << 4);
                s8v kf = *(const s8v*)((const char*)Ks[cur] + r * 128 + (col ^ swz));
#pragma unroll
                for (int g = 0; g < 2; g++)
                    sf[g][kt] = MFMA32(kf, qf[g][st], sf[g][kt]);
            }
        }
        __builtin_amdgcn_s_setprio(0);

        // lane-local online softmax per q-group
#pragma unroll
        for (int g = 0; g < 2; g++) {
            float mx[16];
#pragma unroll
            for (int i = 0; i < 16; i++) mx[i] = fmaxf(sf[g][0][i], sf[g][1][i]);
#pragma unroll
            for (int stp = 8; stp >= 1; stp >>= 1)
#pragma unroll
                for (int i = 0; i < stp; i++) mx[i] = fmaxf(mx[i], mx[i + stp]);
            float tm = fmaxf(mx[0], __shfl_xor(mx[0], 32, 64));

            // defer-max (T13, THR=8)
            if (!__all(tm - m_[g] <= 8.0f)) {
                float mn = fmaxf(m_[g], tm);
                float fac = __builtin_amdgcn_exp2f(m_[g] - mn);
                m_[g] = mn;
                l_[g] *= fac;
#pragma unroll
                for (int dt = 0; dt < 2; dt++)
#pragma unroll
                    for (int i = 0; i < 16; i++) oacc[g][dt][i] *= fac;
            }

            // P = exp2(S - m) in place; row-sum
            float rs0 = 0.f, rs1 = 0.f;
#pragma unroll
            for (int kt = 0; kt < 2; kt++)
#pragma unroll
                for (int i = 0; i < 16; i++) {
                    float p = __builtin_amdgcn_exp2f(sf[g][kt][i] - m_[g]);
                    sf[g][kt][i] = p;
                    if (i & 1) rs1 += p; else rs0 += p;
                }
            float rs = rs0 + rs1;
            rs += __shfl_xor(rs, 32, 64);
            l_[g] += rs;
        }

        // O^T += V^T P^T : per 16-k step build P^T frags in-register, share vf
#pragma unroll
        for (int s = 0; s < 4; s++) {
            const int kt = s >> 1, base = (s & 1) * 8;
            s8v pfrag[2];
#pragma unroll
            for (int g = 0; g < 2; g++) {
                unsigned dA0 = cvt_pk_bf16(sf[g][kt][base + 0], sf[g][kt][base + 1]);
                unsigned dA1 = cvt_pk_bf16(sf[g][kt][base + 2], sf[g][kt][base + 3]);
                unsigned dB0 = cvt_pk_bf16(sf[g][kt][base + 4], sf[g][kt][base + 5]);
                unsigned dB1 = cvt_pk_bf16(sf[g][kt][base + 6], sf[g][kt][base + 7]);
                asm("v_permlane32_swap_b32 %0, %1" : "+v"(dA0), "+v"(dB0));
                asm("v_permlane32_swap_b32 %0, %1" : "+v"(dA1), "+v"(dB1));
                u4v fw = {dA0, dA1, dB0, dB1};
                pfrag[g] = __builtin_bit_cast(s8v, fw);
            }
            __builtin_amdgcn_s_setprio(1);
#pragma unroll
            for (int dt = 0; dt < 2; dt++) {
                int r = dt * 32 + l5;
                int col = (H << 6) | ((s & 1) << 5) | ((s >> 1) << 4);
                s8v vf = *(const s8v*)((const char*)Vs[cur] + r * 128 + (col ^ ((r & 7) << 4)));
#pragma unroll
                for (int g = 0; g < 2; g++)
                    oacc[g][dt] = MFMA32(vf, pfrag[g], oacc[g][dt]);
            }
            __builtin_amdgcn_s_setprio(0);
        }
        __syncthreads();   // drains prefetch (vmcnt) + guards buffer swap
        cur ^= 1;
    }

    // normalize and store bf16 (O^T: q lane-local, d = dt*32 + 8*grp + 4H + j)
#pragma unroll
    for (int g = 0; g < 2; g++) {
        float rl = 1.0f / l_[g];
        size_t orow = (size_t)(b * 2048 + q0 + g * 32 + l5) * 1024 + h * 64;
#pragma unroll
        for (int dt = 0; dt < 2; dt++)
#pragma unroll
            for (int grp = 0; grp < 4; grp++) {
                short4 o;
                o.x = f2bf(oacc[g][dt][4 * grp + 0] * rl);
                o.y = f2bf(oacc[g][dt][4 * grp + 1] * rl);
                o.z = f2bf(oacc[g][dt][4 * grp + 2] * rl);
                o.w = f2bf(oacc[g][dt][4 * grp + 3] * rl);
                *(short4*)(AOb + orow + dt * 32 + grp * 8 + H * 4) = o;
            }
    }
}

// ---------------------------------------------------------------------------
extern "C" void kernel_launch(void* const* d_in, const int* in_sizes, int n_in,
                              void* d_out, int out_size, void* d_ws, size_t ws_size,
                              hipStream_t stream) {
    const float* x  = (const float*)d_in[0];
    const float* wq = (const float*)d_in[1];
    const float* bq = (const float*)d_in[2];
    const float* wk = (const float*)d_in[3];
    const float* bk = (const float*)d_in[4];
    const float* wv = (const float*)d_in[5];
    const float* bv = (const float*)d_in[6];
    const float* wo = (const float*)d_in[7];
    const float* bo = (const float*)d_in[8];
    float* out = (float*)d_out;

    char* ws = (char*)d_ws;
    const size_t MB16 = 16777216;  // 8192*1024*2
    short* xb  = (short*)(ws);              // x bf16 [8192][1024]
    short* qb  = (short*)(ws + 1 * MB16);   // Q bf16 (pre-scaled)
    short* kb  = (short*)(ws + 2 * MB16);   // K bf16
    short* vtb = (short*)(ws + 3 * MB16);   // V transposed bf16
    short* wT  = (short*)(ws + 4 * MB16);   // 4 x WT bf16 (wq,wk,wv,wo)
    short* aob = xb;                        // attention output reuses xb

    const float qscale = 0.125f * 1.4426950408889634f;  // 1/sqrt(64) * log2(e)

    convert_x<<<dim3(1024), dim3(256), 0, stream>>>((const float4*)x, (short4*)xb, 8388608 / 4);
    transpose_w<<<dim3(32, 32, 4), dim3(256), 0, stream>>>(wq, wk, wv, wo, wT);

    gemm_bt<short, 0><<<dim3(8, 64), dim3(256), 0, stream>>>(xb, wT, bq, qb, 8192, 1024, 1024, qscale);
    gemm_bt<short, 0><<<dim3(8, 64), dim3(256), 0, stream>>>(xb, wT + 1048576, bk, kb, 8192, 1024, 1024, 1.0f);
    gemm_bt<short, 1><<<dim3(64, 8), dim3(256), 0, stream>>>(wT + 2 * 1048576, xb, bv, vtb, 1024, 8192, 1024, 1.0f);

    attn_fwd<<<dim3(8, 64), dim3(256), 0, stream>>>(qb, kb, vtb, aob);

    gemm_bt<float, 0><<<dim3(8, 64), dim3(256), 0, stream>>>(aob, wT + 3 * 1048576, bo, out, 8192, 1024, 1024, 1.0f);
}